// Round 1
// baseline (99.195 us; speedup 1.0000x reference)
//
#include <hip/hip_runtime.h>
#include <math.h>

#define NB 32
#define NR 2048
#define NC 91
#define NROWS (NB * NR)

__global__ __launch_bounds__(256) void frcnn_loss_kernel(
    const float* __restrict__ cls, const float* __restrict__ box,
    const int* __restrict__ tgt, const float* __restrict__ btgt,
    double* __restrict__ acc)
{
    const int lane   = threadIdx.x & 63;
    const int wid    = threadIdx.x >> 6;
    const int wave   = (blockIdx.x * blockDim.x + threadIdx.x) >> 6;
    const int nwaves = (gridDim.x * blockDim.x) >> 6;

    float ce_sum = 0.f, hub_sum = 0.f, cnt = 0.f;

    for (int row = wave; row < NROWS; row += nwaves) {
        const float* crow = cls + (size_t)row * NC;
        // coalesced row load: lanes 0..63 then 0..26
        float v0 = crow[lane];
        float v1 = (lane < NC - 64) ? crow[64 + lane] : -INFINITY;
        int   t  = tgt[row];

        // wave max
        float m = fmaxf(v0, v1);
        #pragma unroll
        for (int off = 32; off; off >>= 1) m = fmaxf(m, __shfl_xor(m, off));

        // wave sum of exp
        float e = __expf(v0 - m);
        if (lane < NC - 64) e += __expf(v1 - m);
        #pragma unroll
        for (int off = 32; off; off >>= 1) e += __shfl_xor(e, off);

        if (lane == 0) {
            // ce = logsumexp - x[target]
            ce_sum += __logf(e) + m - crow[t];
        }

        // box loss: gather 4 floats at target class, Huber, positives only
        if (lane < 4 && t > 0) {
            float s  = box[((size_t)row * NC + (size_t)t) * 4 + lane];
            float d  = btgt[(size_t)row * 4 + lane] - s;
            float ad = fabsf(d);
            hub_sum += (ad <= 1.f) ? 0.5f * d * d : (ad - 0.5f);
            cnt     += 1.f;
        }
    }

    // wave butterfly reduce (ce only lane0-nonzero, hub/cnt lanes 0..3)
    #pragma unroll
    for (int off = 32; off; off >>= 1) {
        ce_sum  += __shfl_xor(ce_sum, off);
        hub_sum += __shfl_xor(hub_sum, off);
        cnt     += __shfl_xor(cnt, off);
    }

    __shared__ float s_ce[4], s_h[4], s_c[4];
    if (lane == 0) { s_ce[wid] = ce_sum; s_h[wid] = hub_sum; s_c[wid] = cnt; }
    __syncthreads();
    if (threadIdx.x == 0) {
        float tce = 0.f, th = 0.f, tc = 0.f;
        #pragma unroll
        for (int i = 0; i < 4; ++i) { tce += s_ce[i]; th += s_h[i]; tc += s_c[i]; }
        atomicAdd(&acc[0], (double)tce);
        atomicAdd(&acc[1], (double)th);
        atomicAdd(&acc[2], (double)tc);
    }
}

__global__ void frcnn_finalize(const double* __restrict__ acc,
                               float* __restrict__ out)
{
    if (threadIdx.x == 0) {
        // n_labels = B*R (each one-hot row has exactly one nonzero entry)
        out[0] = (float)(acc[0] / (double)NROWS);
        double c = acc[2];
        out[1] = (float)(c != 0.0 ? acc[1] / c : 0.0);
    }
}

extern "C" void kernel_launch(void* const* d_in, const int* in_sizes, int n_in,
                              void* d_out, int out_size, void* d_ws, size_t ws_size,
                              hipStream_t stream)
{
    const float* cls  = (const float*)d_in[0];
    const float* box  = (const float*)d_in[1];
    const int*   tgt  = (const int*)d_in[2];
    const float* btgt = (const float*)d_in[3];
    float*  out = (float*)d_out;
    double* acc = (double*)d_ws;

    hipMemsetAsync(d_ws, 0, 3 * sizeof(double), stream);
    frcnn_loss_kernel<<<2048, 256, 0, stream>>>(cls, box, tgt, btgt, acc);
    frcnn_finalize<<<1, 64, 0, stream>>>(acc, out);
}

// Round 2
// 54.469 us; speedup vs baseline: 1.8211x; 1.8211x over previous
//
#include <hip/hip_runtime.h>
#include <math.h>

#define NC 91
#define NROWS 65536
#define ROWS_PER_BLK 64
#define NBLK (NROWS / ROWS_PER_BLK)      // 1024
#define TPB 256
#define TILE_FLOATS (ROWS_PER_BLK * NC)  // 5824
#define TILE_F4 (TILE_FLOATS / 4)        // 1456

__global__ __launch_bounds__(TPB) void frcnn_main(
    const float* __restrict__ cls, const float* __restrict__ box,
    const int* __restrict__ tgt, const float* __restrict__ btgt,
    double* __restrict__ acc)
{
    __shared__ float lds[TILE_FLOATS];
    __shared__ float s_ce[4], s_h[4], s_c[4];

    const int tid = threadIdx.x;
    const int blk = blockIdx.x;

    // ---- stage 64-row tile into LDS, coalesced float4 ----
    const float4* src = (const float4*)cls + (size_t)blk * TILE_F4;
    float4* dst = (float4*)lds;
    #pragma unroll
    for (int k = 0; k < 6; ++k) {
        int idx = tid + k * TPB;
        if (idx < TILE_F4) dst[idx] = src[idx];
    }

    const int row  = tid >> 2;           // 0..63
    const int q    = tid & 3;            // 0..3
    const int grow = blk * ROWS_PER_BLK + row;
    const int t    = tgt[grow];          // 4 lanes share addr (broadcast)

    __syncthreads();

    // ---- register-cache my 23 (22 for q==3) elements ----
    const int e0 = q * 23;
    const int ne = (q == 3) ? 22 : 23;
    const float* myrow = lds + row * NC;
    float v[23];
    #pragma unroll
    for (int j = 0; j < 23; ++j)
        v[j] = (j < ne) ? myrow[e0 + j] : -INFINITY;

    // ---- max: local chain + 2-lane-group combine ----
    float m = v[0];
    #pragma unroll
    for (int j = 1; j < 23; ++j) m = fmaxf(m, v[j]);
    m = fmaxf(m, __shfl_xor(m, 1));
    m = fmaxf(m, __shfl_xor(m, 2));

    // ---- sum exp: local from regs + combine ----
    float e = 0.f;
    #pragma unroll
    for (int j = 0; j < 23; ++j) e += __expf(v[j] - m);  // exp(-inf)=0 for pad
    e += __shfl_xor(e, 1);
    e += __shfl_xor(e, 2);

    float ce_s = 0.f, hub = 0.f, cn = 0.f;
    if (q == 0) {
        ce_s = __logf(e) + m - myrow[t];
        if (t > 0) {
            const float4 bo = *(const float4*)(box + ((size_t)grow * NC + t) * 4);
            const float4 bt = *(const float4*)(btgt + (size_t)grow * 4);
            float d, ad;
            d = bt.x - bo.x; ad = fabsf(d); hub += (ad <= 1.f) ? 0.5f*d*d : ad - 0.5f;
            d = bt.y - bo.y; ad = fabsf(d); hub += (ad <= 1.f) ? 0.5f*d*d : ad - 0.5f;
            d = bt.z - bo.z; ad = fabsf(d); hub += (ad <= 1.f) ? 0.5f*d*d : ad - 0.5f;
            d = bt.w - bo.w; ad = fabsf(d); hub += (ad <= 1.f) ? 0.5f*d*d : ad - 0.5f;
            cn = 4.f;
        }
    }

    // ---- wave butterfly reduce (3 values) ----
    #pragma unroll
    for (int off = 32; off; off >>= 1) {
        ce_s += __shfl_xor(ce_s, off);
        hub  += __shfl_xor(hub,  off);
        cn   += __shfl_xor(cn,   off);
    }

    const int wid  = tid >> 6;
    const int lane = tid & 63;
    if (lane == 0) { s_ce[wid] = ce_s; s_h[wid] = hub; s_c[wid] = cn; }
    __syncthreads();
    if (tid == 0) {
        float tce = 0.f, th = 0.f, tc = 0.f;
        #pragma unroll
        for (int i = 0; i < 4; ++i) { tce += s_ce[i]; th += s_h[i]; tc += s_c[i]; }
        atomicAdd(&acc[0], (double)tce);
        atomicAdd(&acc[1], (double)th);
        atomicAdd(&acc[2], (double)tc);
    }
}

__global__ void frcnn_finalize(const double* __restrict__ acc,
                               float* __restrict__ out)
{
    if (threadIdx.x == 0) {
        out[0] = (float)(acc[0] / (double)NROWS);
        double c = acc[2];
        out[1] = (float)(c != 0.0 ? acc[1] / c : 0.0);
    }
}

extern "C" void kernel_launch(void* const* d_in, const int* in_sizes, int n_in,
                              void* d_out, int out_size, void* d_ws, size_t ws_size,
                              hipStream_t stream)
{
    const float* cls  = (const float*)d_in[0];
    const float* box  = (const float*)d_in[1];
    const int*   tgt  = (const int*)d_in[2];
    const float* btgt = (const float*)d_in[3];
    float*  out = (float*)d_out;
    double* acc = (double*)d_ws;

    hipMemsetAsync(d_ws, 0, 3 * sizeof(double), stream);
    frcnn_main<<<NBLK, TPB, 0, stream>>>(cls, box, tgt, btgt, acc);
    frcnn_finalize<<<1, 64, 0, stream>>>(acc, out);
}

// Round 3
// 13.470 us; speedup vs baseline: 7.3641x; 4.0437x over previous
//
#include <hip/hip_runtime.h>
#include <math.h>

#define NC 91
#define NROWS 65536
#define ROWS_PER_BLK 64
#define NBLK (NROWS / ROWS_PER_BLK)      // 1024
#define TPB 256
#define TILE_FLOATS (ROWS_PER_BLK * NC)  // 5824
#define TILE_F4 (TILE_FLOATS / 4)        // 1456

__global__ __launch_bounds__(TPB) void frcnn_main(
    const float* __restrict__ cls, const float* __restrict__ box,
    const int* __restrict__ tgt, const float* __restrict__ btgt,
    float4* __restrict__ partial)
{
    __shared__ float lds[TILE_FLOATS];
    __shared__ float s_ce[4], s_h[4], s_c[4];

    const int tid = threadIdx.x;
    const int blk = blockIdx.x;

    // ---- stage 64-row tile into LDS, coalesced float4 ----
    const float4* src = (const float4*)cls + (size_t)blk * TILE_F4;
    float4* dst = (float4*)lds;
    #pragma unroll
    for (int k = 0; k < 6; ++k) {
        int idx = tid + k * TPB;
        if (idx < TILE_F4) dst[idx] = src[idx];
    }

    const int row  = tid >> 2;           // 0..63
    const int q    = tid & 3;            // 0..3
    const int grow = blk * ROWS_PER_BLK + row;
    const int t    = tgt[grow];          // 4 lanes share addr (broadcast)

    __syncthreads();

    // ---- register-cache my 23 (22 for q==3) elements ----
    const int e0 = q * 23;
    const int ne = (q == 3) ? 22 : 23;
    const float* myrow = lds + row * NC;
    float v[23];
    #pragma unroll
    for (int j = 0; j < 23; ++j)
        v[j] = (j < ne) ? myrow[e0 + j] : -INFINITY;

    // ---- max: local chain + 2-lane-group combine ----
    float m = v[0];
    #pragma unroll
    for (int j = 1; j < 23; ++j) m = fmaxf(m, v[j]);
    m = fmaxf(m, __shfl_xor(m, 1));
    m = fmaxf(m, __shfl_xor(m, 2));

    // ---- sum exp: local from regs + combine ----
    float e = 0.f;
    #pragma unroll
    for (int j = 0; j < 23; ++j) e += __expf(v[j] - m);  // exp(-inf)=0 for pad
    e += __shfl_xor(e, 1);
    e += __shfl_xor(e, 2);

    float ce_s = 0.f, hub = 0.f, cn = 0.f;
    if (q == 0) {
        ce_s = __logf(e) + m - myrow[t];
        if (t > 0) {
            const float4 bo = *(const float4*)(box + ((size_t)grow * NC + t) * 4);
            const float4 bt = *(const float4*)(btgt + (size_t)grow * 4);
            float d, ad;
            d = bt.x - bo.x; ad = fabsf(d); hub += (ad <= 1.f) ? 0.5f*d*d : ad - 0.5f;
            d = bt.y - bo.y; ad = fabsf(d); hub += (ad <= 1.f) ? 0.5f*d*d : ad - 0.5f;
            d = bt.z - bo.z; ad = fabsf(d); hub += (ad <= 1.f) ? 0.5f*d*d : ad - 0.5f;
            d = bt.w - bo.w; ad = fabsf(d); hub += (ad <= 1.f) ? 0.5f*d*d : ad - 0.5f;
            cn = 4.f;
        }
    }

    // ---- wave butterfly reduce (3 values) ----
    #pragma unroll
    for (int off = 32; off; off >>= 1) {
        ce_s += __shfl_xor(ce_s, off);
        hub  += __shfl_xor(hub,  off);
        cn   += __shfl_xor(cn,   off);
    }

    const int wid  = tid >> 6;
    const int lane = tid & 63;
    if (lane == 0) { s_ce[wid] = ce_s; s_h[wid] = hub; s_c[wid] = cn; }
    __syncthreads();
    if (tid == 0) {
        float tce = 0.f, th = 0.f, tc = 0.f;
        #pragma unroll
        for (int i = 0; i < 4; ++i) { tce += s_ce[i]; th += s_h[i]; tc += s_c[i]; }
        partial[blk] = make_float4(tce, th, tc, 0.f);   // unconditional write, no init needed
    }
}

__global__ __launch_bounds__(256) void frcnn_finalize(
    const float4* __restrict__ part, float* __restrict__ out)
{
    const int tid = threadIdx.x;
    double ce = 0.0, h = 0.0, c = 0.0;
    #pragma unroll
    for (int k = 0; k < 4; ++k) {
        float4 p = part[tid + k * 256];
        ce += (double)p.x; h += (double)p.y; c += (double)p.z;
    }
    #pragma unroll
    for (int off = 32; off; off >>= 1) {
        ce += __shfl_xor(ce, off);
        h  += __shfl_xor(h,  off);
        c  += __shfl_xor(c,  off);
    }
    __shared__ double s[12];
    const int wid = tid >> 6, lane = tid & 63;
    if (lane == 0) { s[wid * 3] = ce; s[wid * 3 + 1] = h; s[wid * 3 + 2] = c; }
    __syncthreads();
    if (tid == 0) {
        double tce = 0.0, th = 0.0, tc = 0.0;
        #pragma unroll
        for (int i = 0; i < 4; ++i) { tce += s[i*3]; th += s[i*3+1]; tc += s[i*3+2]; }
        out[0] = (float)(tce / (double)NROWS);
        out[1] = (float)(tc != 0.0 ? th / tc : 0.0);
    }
}

extern "C" void kernel_launch(void* const* d_in, const int* in_sizes, int n_in,
                              void* d_out, int out_size, void* d_ws, size_t ws_size,
                              hipStream_t stream)
{
    const float* cls  = (const float*)d_in[0];
    const float* box  = (const float*)d_in[1];
    const int*   tgt  = (const int*)d_in[2];
    const float* btgt = (const float*)d_in[3];
    float*  out  = (float*)d_out;
    float4* part = (float4*)d_ws;

    frcnn_main<<<NBLK, TPB, 0, stream>>>(cls, box, tgt, btgt, part);
    frcnn_finalize<<<1, 256, 0, stream>>>(part, out);
}

// Round 4
// 12.753 us; speedup vs baseline: 7.7780x; 1.0562x over previous
//
#include <hip/hip_runtime.h>
#include <math.h>

#define NC 91
#define NROWS 65536
#define ROWS_PER_BLK 32
#define NBLK (NROWS / ROWS_PER_BLK)      // 2048
#define TPB 128
#define TILE_FLOATS (ROWS_PER_BLK * NC)  // 2912
#define TILE_F4 (TILE_FLOATS / 4)        // 728

__global__ __launch_bounds__(TPB) void frcnn_main(
    const float* __restrict__ cls, const float* __restrict__ box,
    const int* __restrict__ tgt, const float* __restrict__ btgt,
    float4* __restrict__ partial)
{
    __shared__ float lds[TILE_FLOATS];
    __shared__ float s_ce[2], s_h[2], s_c[2];

    const int tid = threadIdx.x;
    const int blk = blockIdx.x;

    // ---- stage 32-row tile into LDS, coalesced float4 ----
    const float4* src = (const float4*)cls + (size_t)blk * TILE_F4;
    float4* dst = (float4*)lds;
    #pragma unroll
    for (int k = 0; k < 6; ++k) {
        int idx = tid + k * TPB;
        if (idx < TILE_F4) dst[idx] = src[idx];
    }

    const int row  = tid >> 2;           // 0..31
    const int q    = tid & 3;            // 0..3
    const int grow = blk * ROWS_PER_BLK + row;

    // ---- hoisted gathers: overlap with staging drain ----
    const int   t  = tgt[grow];                                  // broadcast across 4 lanes
    const float bo = box[((size_t)grow * NC + t) * 4 + q];       // 4 lanes -> one 16B segment
    const float bt = btgt[(size_t)grow * 4 + q];

    // per-lane Huber (masked by t>0)
    float hub = 0.f, cn = 0.f;
    {
        float d  = bt - bo;
        float ad = fabsf(d);
        float h  = (ad <= 1.f) ? 0.5f * d * d : ad - 0.5f;
        if (t > 0) { hub = h; cn = 1.f; }
    }

    __syncthreads();

    // ---- register-cache my 23 (22 for q==3) elements ----
    const int e0 = q * 23;
    const int ne = (q == 3) ? 22 : 23;
    const float* myrow = lds + row * NC;
    float v[23];
    #pragma unroll
    for (int j = 0; j < 23; ++j)
        v[j] = (j < ne) ? myrow[e0 + j] : -INFINITY;

    // ---- max: local chain + 2 shuffles ----
    float m = v[0];
    #pragma unroll
    for (int j = 1; j < 23; ++j) m = fmaxf(m, v[j]);
    m = fmaxf(m, __shfl_xor(m, 1));
    m = fmaxf(m, __shfl_xor(m, 2));

    // ---- sum exp from regs + 2 shuffles ----
    float e = 0.f;
    #pragma unroll
    for (int j = 0; j < 23; ++j) e += __expf(v[j] - m);  // exp(-inf)=0 for pad
    e += __shfl_xor(e, 1);
    e += __shfl_xor(e, 2);

    float ce_s = 0.f;
    if (q == 0) ce_s = __logf(e) + m - myrow[t];

    // ---- wave butterfly reduce (3 values) ----
    #pragma unroll
    for (int off = 32; off; off >>= 1) {
        ce_s += __shfl_xor(ce_s, off);
        hub  += __shfl_xor(hub,  off);
        cn   += __shfl_xor(cn,   off);
    }

    const int wid  = tid >> 6;           // 0..1
    const int lane = tid & 63;
    if (lane == 0) { s_ce[wid] = ce_s; s_h[wid] = hub; s_c[wid] = cn; }
    __syncthreads();
    if (tid == 0) {
        float tce = s_ce[0] + s_ce[1];
        float th  = s_h[0]  + s_h[1];
        float tc  = s_c[0]  + s_c[1];
        partial[blk] = make_float4(tce, th, tc, 0.f);   // unconditional, no init needed
    }
}

__global__ __launch_bounds__(256) void frcnn_finalize(
    const float4* __restrict__ part, float* __restrict__ out)
{
    const int tid = threadIdx.x;
    double ce = 0.0, h = 0.0, c = 0.0;
    #pragma unroll
    for (int k = 0; k < 8; ++k) {
        float4 p = part[tid + k * 256];
        ce += (double)p.x; h += (double)p.y; c += (double)p.z;
    }
    #pragma unroll
    for (int off = 32; off; off >>= 1) {
        ce += __shfl_xor(ce, off);
        h  += __shfl_xor(h,  off);
        c  += __shfl_xor(c,  off);
    }
    __shared__ double s[12];
    const int wid = tid >> 6, lane = tid & 63;
    if (lane == 0) { s[wid * 3] = ce; s[wid * 3 + 1] = h; s[wid * 3 + 2] = c; }
    __syncthreads();
    if (tid == 0) {
        double tce = 0.0, th = 0.0, tc = 0.0;
        #pragma unroll
        for (int i = 0; i < 4; ++i) { tce += s[i*3]; th += s[i*3+1]; tc += s[i*3+2]; }
        out[0] = (float)(tce / (double)NROWS);
        out[1] = (float)(tc != 0.0 ? th / tc : 0.0);
    }
}

extern "C" void kernel_launch(void* const* d_in, const int* in_sizes, int n_in,
                              void* d_out, int out_size, void* d_ws, size_t ws_size,
                              hipStream_t stream)
{
    const float* cls  = (const float*)d_in[0];
    const float* box  = (const float*)d_in[1];
    const int*   tgt  = (const int*)d_in[2];
    const float* btgt = (const float*)d_in[3];
    float*  out  = (float*)d_out;
    float4* part = (float4*)d_ws;

    frcnn_main<<<NBLK, TPB, 0, stream>>>(cls, box, tgt, btgt, part);
    frcnn_finalize<<<1, 256, 0, stream>>>(part, out);
}